// Round 3
// baseline (85.869 us; speedup 1.0000x reference)
//
#include <hip/hip_runtime.h>

#define BLOCK 256
#define SPLITS 16
#define QPT 8      // queries per thread (register blocking)
#define MAXC 264   // padded candidate-chunk capacity (m <= 4096)

// d2(q,c) = (qx-cx)^2+(qy-cy)^2 = q2 + (c2 - 2*qx*cx - 2*qy*cy).
// All terms are integers < 2^24 for valid candidates -> fp32 exact.
// Sentinel candidates (3e4) give t >= 1.7e9 >> max valid t (5.3e5): never win.

__global__ __launch_bounds__(BLOCK) void partial_kernel(
    const int* __restrict__ li_coors, int n_li,
    const int* __restrict__ ra_coors, int n_ra,
    const float* __restrict__ pts,
    const int* __restrict__ vox,
    int m, int cs, int csPad,
    float* __restrict__ partials,   // [SPLITS][total] in d_ws
    int* __restrict__ counter)      // zero-initialized, in d_ws
{
    __shared__ float2 sc[MAXC];

    // Stage this split's candidate chunk (packed x,y; invalid/pad -> sentinel).
    const int split = blockIdx.y;
    const int base = split * cs;
    int nvalid = 0;
    for (int i = threadIdx.x; i < csPad; i += BLOCK) {
        int gi = base + i;
        float x = 3.0e4f, y = 3.0e4f;
        if (i < cs && gi < m) {
            if (fabsf(pts[gi * 5 + 4]) > 0.1f) {
                x = (float)vox[gi * 3 + 1];
                y = (float)vox[gi * 3 + 2];
                nvalid++;
            }
        }
        sc[i] = make_float2(x, y);
    }
    // Each candidate counted exactly once (only the blockIdx.x==0 column).
    if (blockIdx.x == 0 && nvalid) atomicAdd(counter, nvalid);
    __syncthreads();

    const int li_total = n_li * 9;
    const int total = (n_li + n_ra) * 9;
    const int qbase = blockIdx.x * (BLOCK * QPT) + threadIdx.x;

    float n2x[QPT], n2y[QPT], q2[QPT], m0[QPT], m1[QPT];
#pragma unroll
    for (int k = 0; k < QPT; ++k) {
        int q = qbase + k * BLOCK;
        float qx = 0.0f, qy = 0.0f;
        if (q < total) {
            const int shift_x[9] = {0,-1,1,0,-1,1,0,-1,1};
            const int shift_y[9] = {0, 0,0,1, 1,1,-1,-1,-1};
            int n, s;
            const int* src;
            if (q < li_total) { n = q / 9; s = q - n * 9; src = li_coors; }
            else { int r = q - li_total; n = r / 9; s = r - n * 9; src = ra_coors; }
            int cx = src[n * 2 + 0] + shift_x[s];
            int cy = src[n * 2 + 1] + shift_y[s];
            if (cx < 0) cx += 513;   // coords in [0,511], shift in {-1,0,1}
            if (cy < 0) cy += 513;
            qx = (float)cx; qy = (float)cy;
        }
        n2x[k] = -2.0f * qx;
        n2y[k] = -2.0f * qy;
        q2[k]  = fmaf(qx, qx, qy * qy);
        m0[k] = 3.4e38f; m1[k] = 3.4e38f;
    }

    // 2 candidates per ds_read_b128, amortized over 8 queries; 16 min-chains.
    const float4* __restrict__ s4 = (const float4*)sc;
    const int iters = csPad >> 1;
    for (int i = 0; i < iters; ++i) {
        float4 a = s4[i];
        float c2a = fmaf(a.x, a.x, a.y * a.y);
        float c2b = fmaf(a.z, a.z, a.w * a.w);
#pragma unroll
        for (int k = 0; k < QPT; ++k) {
            float ta = fmaf(a.x, n2x[k], fmaf(a.y, n2y[k], c2a));
            float tb = fmaf(a.z, n2x[k], fmaf(a.w, n2y[k], c2b));
            m0[k] = fminf(m0[k], ta);
            m1[k] = fminf(m1[k], tb);
        }
    }

    float* __restrict__ dst = partials + (size_t)split * total;
#pragma unroll
    for (int k = 0; k < QPT; ++k) {
        int q = qbase + k * BLOCK;
        if (q < total) dst[q] = q2[k] + fminf(m0[k], m1[k]);
    }
}

__global__ __launch_bounds__(BLOCK) void finalize_kernel(
    const float* __restrict__ partials, int total,
    const int* __restrict__ counter, float* __restrict__ out)
{
    int q = blockIdx.x * BLOCK + threadIdx.x;
    if (q >= total) return;
    float best = 3.4e38f;
#pragma unroll
    for (int s = 0; s < SPLITS; ++s)
        best = fminf(best, partials[(size_t)s * total + q]);
    out[q] = (*counter > 1) ? sqrtf(best) * 0.01f : 0.0f;
}

extern "C" void kernel_launch(void* const* d_in, const int* in_sizes, int n_in,
                              void* d_out, int out_size, void* d_ws, size_t ws_size,
                              hipStream_t stream) {
    const int*   li  = (const int*)d_in[0];
    const int*   ra  = (const int*)d_in[1];
    const float* pts = (const float*)d_in[2];
    const int*   vox = (const int*)d_in[3];
    float* out = (float*)d_out;

    int*   counter  = (int*)d_ws;
    float* partials = (float*)((char*)d_ws + 256);

    const int n_li = in_sizes[0] / 2;
    const int n_ra = in_sizes[1] / 2;
    const int m    = in_sizes[2] / 5;

    const int total = (n_li + n_ra) * 9;                       // 92160
    const int qblocks = (total + BLOCK * QPT - 1) / (BLOCK * QPT);   // 45
    const int fblocks = (total + BLOCK - 1) / BLOCK;           // 360

    const int cs    = (m + SPLITS - 1) / SPLITS;               // 128
    const int csPad = (cs + 7) & ~7;

    hipMemsetAsync(d_ws, 0, sizeof(int), stream);

    dim3 grid(qblocks, SPLITS);
    partial_kernel<<<grid, BLOCK, 0, stream>>>(li, n_li, ra, n_ra, pts, vox,
                                               m, cs, csPad, partials, counter);
    finalize_kernel<<<fblocks, BLOCK, 0, stream>>>(partials, total, counter, out);
}

// Round 4
// 83.214 us; speedup vs baseline: 1.0319x; 1.0319x over previous
//
#include <hip/hip_runtime.h>

#define BLOCK 256
#define SPLITS 32
#define QPT 8      // queries per thread (register blocking)
#define MAXC 264   // padded candidate-chunk capacity

// d2(q,c) = (qx-cx)^2+(qy-cy)^2 = q2 + (c2 - 2*qx*cx - 2*qy*cy).
// All terms are integers < 2^24 for valid candidates -> fp32 exact.
// Sentinel candidates (3e4) give t >= 1.7e9 >> max valid t (5.3e5): never win.

__global__ __launch_bounds__(BLOCK) void partial_kernel(
    const int* __restrict__ li_coors, int n_li,
    const int* __restrict__ ra_coors, int n_ra,
    const float* __restrict__ pts,
    const int* __restrict__ vox,
    int m, int cs, int csPad,
    float* __restrict__ partials,   // [SPLITS][total] in d_ws
    int* __restrict__ counts)       // [SPLITS] in d_ws (plain stores, no init)
{
    __shared__ __align__(16) float2 sc[MAXC];
    __shared__ int s_cnt;

    if (threadIdx.x == 0) s_cnt = 0;
    __syncthreads();

    // Stage this split's candidate chunk (packed x,y; invalid/pad -> sentinel).
    const int split = blockIdx.y;
    const int base = split * cs;
    int nvalid = 0;
    for (int i = threadIdx.x; i < csPad; i += BLOCK) {
        int gi = base + i;
        float x = 3.0e4f, y = 3.0e4f;
        if (i < cs && gi < m) {
            if (fabsf(pts[gi * 5 + 4]) > 0.1f) {
                x = (float)vox[gi * 3 + 1];
                y = (float)vox[gi * 3 + 2];
                nvalid++;
            }
        }
        sc[i] = make_float2(x, y);
    }
    if (nvalid) atomicAdd(&s_cnt, nvalid);   // LDS atomic, wave-coalesced
    __syncthreads();
    // Block (0, split) publishes its chunk's count: every slot written each
    // launch via plain store -> no zero-init of ws needed.
    if (blockIdx.x == 0 && threadIdx.x == 0) counts[split] = s_cnt;

    const int li_total = n_li * 9;
    const int total = (n_li + n_ra) * 9;
    const int qbase = blockIdx.x * (BLOCK * QPT) + threadIdx.x;

    float n2x[QPT], n2y[QPT], q2[QPT], mn[QPT];
#pragma unroll
    for (int k = 0; k < QPT; ++k) {
        int q = qbase + k * BLOCK;
        float qx = 0.0f, qy = 0.0f;
        if (q < total) {
            const int shift_x[9] = {0,-1,1,0,-1,1,0,-1,1};
            const int shift_y[9] = {0, 0,0,1, 1,1,-1,-1,-1};
            int n, s;
            const int* src;
            if (q < li_total) { n = q / 9; s = q - n * 9; src = li_coors; }
            else { int r = q - li_total; n = r / 9; s = r - n * 9; src = ra_coors; }
            int cx = src[n * 2 + 0] + shift_x[s];
            int cy = src[n * 2 + 1] + shift_y[s];
            if (cx < 0) cx += 513;   // coords in [0,511], shift in {-1,0,1}
            if (cy < 0) cy += 513;
            qx = (float)cx; qy = (float)cy;
        }
        n2x[k] = -2.0f * qx;
        n2y[k] = -2.0f * qy;
        q2[k]  = fmaf(qx, qx, qy * qy);
        mn[k]  = 3.4e38f;
    }

    // 2 candidates per ds_read_b128 amortized over 8 queries; v_min3 merge.
    const float4* __restrict__ s4 = (const float4*)sc;
    const int iters = csPad >> 1;
    for (int i = 0; i < iters; ++i) {
        float4 a = s4[i];
        float c2a = fmaf(a.x, a.x, a.y * a.y);
        float c2b = fmaf(a.z, a.z, a.w * a.w);
#pragma unroll
        for (int k = 0; k < QPT; ++k) {
            float ta = fmaf(a.x, n2x[k], fmaf(a.y, n2y[k], c2a));
            float tb = fmaf(a.z, n2x[k], fmaf(a.w, n2y[k], c2b));
            mn[k] = fminf(fminf(ta, tb), mn[k]);   // v_min3_f32
        }
    }

    float* __restrict__ dst = partials + (size_t)split * total;
#pragma unroll
    for (int k = 0; k < QPT; ++k) {
        int q = qbase + k * BLOCK;
        if (q < total) dst[q] = q2[k] + mn[k];
    }
}

__global__ __launch_bounds__(BLOCK) void finalize_kernel(
    const float* __restrict__ partials, int total,
    const int* __restrict__ counts, float* __restrict__ out)
{
    int q = blockIdx.x * BLOCK + threadIdx.x;
    if (q >= total) return;
    int cnt = 0;
#pragma unroll
    for (int s = 0; s < SPLITS; ++s) cnt += counts[s];   // scalar broadcast
    float best = 3.4e38f;
#pragma unroll
    for (int s = 0; s < SPLITS; ++s)
        best = fminf(best, partials[(size_t)s * total + q]);
    out[q] = (cnt > 1) ? sqrtf(best) * 0.01f : 0.0f;
}

extern "C" void kernel_launch(void* const* d_in, const int* in_sizes, int n_in,
                              void* d_out, int out_size, void* d_ws, size_t ws_size,
                              hipStream_t stream) {
    const int*   li  = (const int*)d_in[0];
    const int*   ra  = (const int*)d_in[1];
    const float* pts = (const float*)d_in[2];
    const int*   vox = (const int*)d_in[3];
    float* out = (float*)d_out;

    const int n_li = in_sizes[0] / 2;
    const int n_ra = in_sizes[1] / 2;
    const int m    = in_sizes[2] / 5;

    const int total = (n_li + n_ra) * 9;                           // 92160
    const int qblocks = (total + BLOCK * QPT - 1) / (BLOCK * QPT); // 45
    const int fblocks = (total + BLOCK - 1) / BLOCK;               // 360

    const int cs    = (m + SPLITS - 1) / SPLITS;                   // 64
    const int csPad = (cs + 7) & ~7;

    float* partials = (float*)d_ws;
    int*   counts   = (int*)((char*)d_ws + (size_t)SPLITS * total * sizeof(float));

    dim3 grid(qblocks, SPLITS);
    partial_kernel<<<grid, BLOCK, 0, stream>>>(li, n_li, ra, n_ra, pts, vox,
                                               m, cs, csPad, partials, counts);
    finalize_kernel<<<fblocks, BLOCK, 0, stream>>>(partials, total, counts, out);
}